// Round 12
// baseline (101.576 us; speedup 1.0000x reference)
//
#include <hip/hip_runtime.h>

// AttentionBlock: B=8, C=256, S=2048, H=4, DK=64
// k_prep (transpose+cast x -> xt [chunk-swizzled], weight casts; wp chunk-swizzled)
// -> k_qkv (LDS-staged A/B via global_load_lds, LDS-repacked coalesced outputs)
// -> k_attn (LDS double-buffered KV, counted vmcnt(8) + RAW s_barrier pipeline)
// -> k_out (GEMM + bias + residual). fp16 storage, fp32 MFMA accum.
// Softmax: constant-shift exp2 (scale*log2e folded into Q, shift in MFMA C-init),
// raw v_exp_f32, denominator via ones-row MFMA (permuted-k K=32 PV).

typedef _Float16 f16;
typedef __attribute__((ext_vector_type(4))) float f32x4;
typedef __attribute__((ext_vector_type(8))) _Float16 h8;
typedef __attribute__((ext_vector_type(4))) _Float16 h4;
typedef __attribute__((ext_vector_type(2))) __fp16 fp16x2;
typedef __attribute__((ext_vector_type(4))) __fp16 fp16x4;
typedef __attribute__((ext_vector_type(8))) __fp16 fp16x8;

#define SS 2048
#define CC 256
#define BB 8
#define HH 4
#define DK 64
#define O3 768
#define NT64 32  // 32 tiles of 64 keys; tile = 4096 f16 (8KB) each for K and V
#define C1F 0.1803368801111204f   // 0.125 * log2(e)
#define C2L2 11.541560327111707f  // 8 * log2(e)

#define MFMA32(a, b, c) __builtin_amdgcn_mfma_f32_16x16x32_f16(a, b, c, 0, 0, 0)

#if __has_builtin(__builtin_amdgcn_exp2f)
#define EXP2(x) __builtin_amdgcn_exp2f(x)  // raw v_exp_f32 (args in [-40,-3]: safe)
#else
#define EXP2(x) exp2f(x)
#endif

__device__ __forceinline__ void async_ld16(const f16* g, f16* lds) {
  __builtin_amdgcn_global_load_lds(
      (const __attribute__((address_space(1))) unsigned int*)g,
      (__attribute__((address_space(3))) unsigned int*)lds, 16, 0, 0);
}

// ---------------- prep ----------------
// z<8 : xt[b][s][swizzled c] = (f16) x[b][c][s]
// z==8: weight casts; wp rows chunk-swizzled, wo plain (k_out reads it directly)
__global__ __launch_bounds__(256) void k_prep(const float* __restrict__ x,
                                              f16* __restrict__ xt,
                                              const float* __restrict__ w_proj,
                                              const float* __restrict__ w_out,
                                              f16* __restrict__ wp, f16* __restrict__ wo) {
  if (blockIdx.z == 8) {
    int slice = blockIdx.y * 32 + blockIdx.x;  // 0..127
    int i0 = slice * 2048 + threadIdx.x * 8;
    const float* src;
    f16* dst;
    if (i0 < O3 * CC) {
      src = w_proj + i0;
      int row = i0 >> 8, ch = (i0 & 255) >> 3;
      dst = wp + row * 256 + ((ch ^ (row & 7)) << 3);
    } else {
      int j = i0 - O3 * CC;
      src = w_out + j;
      dst = wo + j;
    }
    float4 a = *(const float4*)src;
    float4 b = *(const float4*)(src + 4);
    h8 v = {(f16)a.x, (f16)a.y, (f16)a.z, (f16)a.w,
            (f16)b.x, (f16)b.y, (f16)b.z, (f16)b.w};
    *(h8*)dst = v;
    return;
  }
  __shared__ float tile[64][65];
  int b = blockIdx.z, c0 = blockIdx.y * 64, s0 = blockIdx.x * 64;
  int t = threadIdx.x;
#pragma unroll
  for (int it = 0; it < 16; ++it) {
    int idx = it * 256 + t;
    int cl = idx >> 6, sl = idx & 63;
    tile[cl][sl] = x[(size_t)(b * CC + c0 + cl) * SS + s0 + sl];
  }
  __syncthreads();
  // 512 chunk-stores (64 s x 8 chunks), 2 per thread; 16B each, swizzled position
#pragma unroll
  for (int cid = t; cid < 512; cid += 256) {
    int sl = cid >> 3, chl = cid & 7;
    int s = s0 + sl;
    int gch = (c0 >> 3) + chl;
    h8 v;
#pragma unroll
    for (int e = 0; e < 8; ++e) v[e] = (f16)tile[chl * 8 + e][sl];
    *(h8*)(xt + (size_t)(b * SS + s) * CC + ((gch ^ (s & 7)) << 3)) = v;
  }
}

// ---------------- QKV GEMM (LDS-staged, coalesced in AND out) ----------------
__global__ __launch_bounds__(256) void k_qkv(const f16* __restrict__ xt,
                                             const f16* __restrict__ wp,
                                             const float* __restrict__ bp,
                                             f16* __restrict__ qh, f16* __restrict__ ksw,
                                             f16* __restrict__ vsw) {
  __shared__ f16 As[16384];  // 64 x 256 (32KB)
  __shared__ f16 Bs[16384];  // 64 x 256 (32KB)
  __shared__ f16 Ot[4096];   // 8KB out staging
  int b = blockIdx.z;
  int oti = blockIdx.y, o0 = oti * 64;
  int s0 = blockIdx.x * 64;
  int w = threadIdx.x >> 6, l = threadIdx.x & 63;
  int lr = l & 15, lg = l >> 4;

  const f16* Ag = xt + ((size_t)b * SS + s0) * CC;  // 32KB contiguous
  const f16* Bg = wp + (size_t)o0 * CC;
#pragma unroll
  for (int i = 0; i < 8; ++i) {
    int off = w * 4096 + i * 512;
    async_ld16(Ag + off + l * 8, &As[off]);
    async_ld16(Bg + off + l * 8, &Bs[off]);
  }
  asm volatile("s_waitcnt vmcnt(0)" ::: "memory");
  __syncthreads();

  f32x4 acc[4] = {};
#pragma unroll
  for (int kk = 0; kk < CC; kk += 32) {
    int chs = (((kk >> 3) + lg) ^ (lr & 7)) << 3;
    h8 af = *(const h8*)&As[(w * 16 + lr) * 256 + chs];
#pragma unroll
    for (int n = 0; n < 4; ++n) {
      h8 bf = *(const h8*)&Bs[(n * 16 + lr) * 256 + chs];
      acc[n] = MFMA32(af, bf, acc[n]);
    }
  }

  int seg = oti % 3;  // 0=q 1=k 2=v
  int h = oti / 3;
  int bh = b * HH + h;
  float scl = (seg == 0) ? C1F : 1.0f;
#pragma unroll
  for (int n = 0; n < 4; ++n) {
    float bb = bp[o0 + n * 16 + lr];
#pragma unroll
    for (int r = 0; r < 4; ++r) acc[n][r] = (acc[n][r] + bb) * scl;
  }

  // repack D into Ot at target layout (wave-disjoint addresses)
  if (seg == 2) {
#pragma unroll
    for (int n = 0; n < 4; ++n) {
      int d = n * 16 + lr;
#pragma unroll
      for (int r = 0; r < 4; ++r) {
        int sl = w * 16 + lg * 4 + r;
        int kl = sl & 31;
        int ps = ((kl & 15) >> 2) ^ ((d >> 1) & 3);
        Ot[(sl >> 5) * 2048 + d * 32 + ps * 8 + ((kl >> 4) << 2) + (kl & 3)] =
            (f16)acc[n][r];
      }
    }
  } else if (seg == 1) {
#pragma unroll
    for (int n = 0; n < 4; ++n) {
      int d = n * 16 + lr;
#pragma unroll
      for (int r = 0; r < 4; ++r) {
        int sl = w * 16 + lg * 4 + r;
        int kl = sl & 31;
        Ot[(sl >> 5) * 2048 + kl * 64 + (((d >> 3) ^ (kl & 7)) << 3) + (d & 7)] =
            (f16)acc[n][r];
      }
    }
  } else {
#pragma unroll
    for (int n = 0; n < 4; ++n)
#pragma unroll
      for (int r = 0; r < 4; ++r)
        Ot[(w * 16 + lg * 4 + r) * 64 + n * 16 + lr] = (f16)acc[n][r];
  }
  __syncthreads();

  int t = threadIdx.x;
  f16* dst;
  if (seg == 0)
    dst = qh + ((size_t)bh * SS + s0) * DK;
  else if (seg == 1)
    dst = ksw + ((size_t)bh * NT64 + (s0 >> 6)) * 4096;
  else
    dst = vsw + ((size_t)bh * NT64 + (s0 >> 6)) * 4096;
  *(int4*)(dst + t * 16) = *(const int4*)&Ot[t * 16];
  *(int4*)(dst + t * 16 + 8) = *(const int4*)&Ot[t * 16 + 8];
}

// ---------------- attention (counted-vmcnt + raw-barrier pipeline) ----------------
// Block: 2 waves x 32 queries; 1024 blocks = 4/CU. Double-buffered 64-key tiles.
// Pipeline: STAGE(0,0),STAGE(1,1) -> loop{ vmcnt(8); s_barrier; compute(buf[kt&1]);
// s_barrier; STAGE(buf[kt&1], kt+2) }. vmcnt(8) only waits the tile being read;
// the next tile's 8 loads stay in flight across both barriers (no drain-to-0).
// Raw __builtin_amdgcn_s_barrier (no implicit vmcnt(0) drain, unlike __syncthreads);
// sched_barrier(0) fences stop the compiler moving memory ops across barriers.
__global__ __launch_bounds__(128) void k_attn(const f16* __restrict__ qh,
                                              const f16* __restrict__ ksw,
                                              const f16* __restrict__ vsw,
                                              f16* __restrict__ res) {
  __shared__ f16 kbuf[2][4096];
  __shared__ f16 vbuf[2][4096];
  int id = blockIdx.x;
  int xcd = id & 7, slot = id >> 3;  // 128 slots per XCD
  int bh = xcd * 4 + (slot >> 5);    // 4 heads per XCD -> K/V L2-resident
  int qt = slot & 31;
  int w = threadIdx.x >> 6, l = threadIdx.x & 63;
  int q0 = qt * 64 + w * 32;
  int lr = l & 15, lg = l >> 4;

  h8 qf[2][2];
#pragma unroll
  for (int t = 0; t < 2; ++t) {
    const f16* qp = qh + (size_t)(bh * SS + q0 + t * 16 + lr) * DK;
    qf[t][0] = *(const h8*)(qp + lg * 8);
    qf[t][1] = *(const h8*)(qp + 32 + lg * 8);
  }

  const f16* kg = ksw + (size_t)bh * (SS * DK);
  const f16* vg = vsw + (size_t)bh * (SS * DK);

#define STAGE(bufi, tile)                                           \
  {                                                                 \
    const f16* kq = kg + (size_t)(tile) * 4096 + w * 2048 + l * 8;  \
    const f16* vq = vg + (size_t)(tile) * 4096 + w * 2048 + l * 8;  \
    f16* kd = &kbuf[bufi][w * 2048];                                \
    f16* vd = &vbuf[bufi][w * 2048];                                \
    async_ld16(kq, kd);                                             \
    async_ld16(kq + 512, kd + 512);                                 \
    async_ld16(kq + 1024, kd + 1024);                               \
    async_ld16(kq + 1536, kd + 1536);                               \
    async_ld16(vq, vd);                                             \
    async_ld16(vq + 512, vd + 512);                                 \
    async_ld16(vq + 1024, vd + 1024);                               \
    async_ld16(vq + 1536, vd + 1536);                               \
  }

  int swk = (lr & 7) << 3;
  int ek[2][2];
#pragma unroll
  for (int kb = 0; kb < 2; ++kb)
#pragma unroll
    for (int ch = 0; ch < 2; ++ch)
      ek[kb][ch] = (lr + kb * 16) * 64 + ((ch * 32 + lg * 8) ^ swk);
  int ev = lr * 32 + ((lg ^ ((lr >> 1) & 3)) * 8);  // + m*512

  f32x4 oacc[2][4] = {};
  f32x4 dacc[2] = {};
  const f32x4 cinit = {-C2L2, -C2L2, -C2L2, -C2L2};
  const h8 ones8 = {(f16)1.0f, (f16)1.0f, (f16)1.0f, (f16)1.0f,
                    (f16)1.0f, (f16)1.0f, (f16)1.0f, (f16)1.0f};

  // prologue: two tiles in flight (16 outstanding loads per wave)
  STAGE(0, 0);
  STAGE(1, 1);

  for (int kt = 0; kt < NT64; ++kt) {
    int cur = kt & 1;
    // wait ONLY for tile kt's 8 loads (8 of tile kt+1 remain in flight)
    asm volatile("s_waitcnt vmcnt(8)" ::: "memory");
    __builtin_amdgcn_sched_barrier(0);
    __builtin_amdgcn_s_barrier();  // both waves' tile-kt loads landed
    __builtin_amdgcn_sched_barrier(0);

    const f16* kb_ = kbuf[cur];
    const f16* vb_ = vbuf[cur];
#pragma unroll
    for (int sub = 0; sub < 2; ++sub) {
      int sb = sub * 2048;
      h8 kf[2][2];
#pragma unroll
      for (int kb = 0; kb < 2; ++kb)
#pragma unroll
        for (int ch = 0; ch < 2; ++ch) kf[kb][ch] = *(const h8*)&kb_[sb + ek[kb][ch]];
      h8 vv[4];
#pragma unroll
      for (int m = 0; m < 4; ++m) vv[m] = *(const h8*)&vb_[sb + ev + m * 512];

      __builtin_amdgcn_s_setprio(1);
      f32x4 sacc[2][2];
#pragma unroll
      for (int t = 0; t < 2; ++t)
#pragma unroll
        for (int kb = 0; kb < 2; ++kb) {
          sacc[t][kb] = MFMA32(kf[kb][0], qf[t][0], cinit);
          sacc[t][kb] = MFMA32(kf[kb][1], qf[t][1], sacc[t][kb]);
        }
      h8 pf8[2];
#pragma unroll
      for (int t = 0; t < 2; ++t) {
        float e0 = EXP2(sacc[t][0][0]);
        float e1 = EXP2(sacc[t][0][1]);
        float e2 = EXP2(sacc[t][0][2]);
        float e3 = EXP2(sacc[t][0][3]);
        float e4 = EXP2(sacc[t][1][0]);
        float e5 = EXP2(sacc[t][1][1]);
        float e6 = EXP2(sacc[t][1][2]);
        float e7 = EXP2(sacc[t][1][3]);
        fp16x2 p01 = __builtin_amdgcn_cvt_pkrtz(e0, e1);
        fp16x2 p23 = __builtin_amdgcn_cvt_pkrtz(e2, e3);
        fp16x2 p45 = __builtin_amdgcn_cvt_pkrtz(e4, e5);
        fp16x2 p67 = __builtin_amdgcn_cvt_pkrtz(e6, e7);
        fp16x4 lo4 = __builtin_shufflevector(p01, p23, 0, 1, 2, 3);
        fp16x4 hi4 = __builtin_shufflevector(p45, p67, 0, 1, 2, 3);
        fp16x8 p8 = __builtin_shufflevector(lo4, hi4, 0, 1, 2, 3, 4, 5, 6, 7);
        pf8[t] = __builtin_bit_cast(h8, p8);
      }
#pragma unroll
      for (int t = 0; t < 2; ++t) dacc[t] = MFMA32(ones8, pf8[t], dacc[t]);
#pragma unroll
      for (int t = 0; t < 2; ++t)
#pragma unroll
        for (int m = 0; m < 4; ++m) oacc[t][m] = MFMA32(vv[m], pf8[t], oacc[t][m]);
      __builtin_amdgcn_s_setprio(0);
    }

    __builtin_amdgcn_sched_barrier(0);
    __builtin_amdgcn_s_barrier();  // all waves done READING buf[cur]
    __builtin_amdgcn_sched_barrier(0);
    // refill the buffer just freed; loads may land any time before iter kt+2's wait
    int nxt = (kt + 2) & (NT64 - 1);
    STAGE(cur, nxt);
  }

  int b = bh >> 2, h = bh & 3;
#pragma unroll
  for (int t = 0; t < 2; ++t) {
    float inv = 1.0f / dacc[t][0];  // every lane holds its own q-column's sum
    f16* rp = res + (size_t)(b * SS + q0 + t * 16 + lr) * CC + h * DK + lg * 4;
#pragma unroll
    for (int m = 0; m < 4; ++m) {
      h4 rv;
#pragma unroll
      for (int r = 0; r < 4; ++r) rv[r] = (f16)(oacc[t][m][r] * inv);
      *(h4*)(rp + m * 16) = rv;
    }
  }
}

// ---------------- out GEMM + bias + residual (unchanged) ----------------
__global__ __launch_bounds__(256) void k_out(const f16* __restrict__ res,
                                             const f16* __restrict__ wo,
                                             const float* __restrict__ bo,
                                             const float* __restrict__ x,
                                             float* __restrict__ out) {
  int b = blockIdx.z;
  int c0 = blockIdx.y * 64;
  int w = threadIdx.x >> 6, l = threadIdx.x & 63;
  int s0 = blockIdx.x * 64 + w * 16;
  int lr = l & 15, lg = l >> 4;

  const f16* aptr = res + (size_t)(b * SS + s0 + lr) * CC;
  const f16* bptr = wo + (size_t)(c0 + lr) * CC;
  f32x4 acc[4] = {};
#pragma unroll
  for (int kk = 0; kk < CC; kk += 32) {
    h8 af = *(const h8*)(aptr + kk + lg * 8);
#pragma unroll
    for (int n = 0; n < 4; ++n) {
      h8 bf = *(const h8*)(bptr + n * 16 * CC + kk + lg * 8);
      acc[n] = MFMA32(af, bf, acc[n]);
    }
  }
#pragma unroll
  for (int n = 0; n < 4; ++n) {
    int c = c0 + n * 16 + lr;
    float bb = bo[c];
    const float* xp = x + (size_t)(b * CC + c) * SS + s0 + lg * 4;
    float4 xv = *(const float4*)xp;
    float4 ov;
    ov.x = acc[n][0] + bb + xv.x;
    ov.y = acc[n][1] + bb + xv.y;
    ov.z = acc[n][2] + bb + xv.z;
    ov.w = acc[n][3] + bb + xv.w;
    *(float4*)(out + (size_t)(b * CC + c) * SS + s0 + lg * 4) = ov;
  }
}

extern "C" void kernel_launch(void* const* d_in, const int* in_sizes, int n_in,
                              void* d_out, int out_size, void* d_ws, size_t ws_size,
                              hipStream_t stream) {
  const float* x = (const float*)d_in[0];
  const float* w_proj = (const float*)d_in[1];
  const float* b_proj = (const float*)d_in[2];
  const float* w_out = (const float*)d_in[3];
  const float* b_out = (const float*)d_in[4];
  float* out = (float*)d_out;

  char* p = (char*)d_ws;
  f16* xt = (f16*)p; p += (size_t)BB * SS * CC * 2;
  f16* wp = (f16*)p; p += (size_t)O3 * CC * 2;
  f16* wo = (f16*)p; p += (size_t)CC * CC * 2;
  f16* qh = (f16*)p; p += (size_t)BB * HH * SS * DK * 2;
  f16* ksw = (f16*)p; p += (size_t)BB * HH * SS * DK * 2;
  f16* vsw = (f16*)p; p += (size_t)BB * HH * SS * DK * 2;
  f16* res = (f16*)p;

  k_prep<<<dim3(SS / 64, CC / 64, BB + 1), 256, 0, stream>>>(x, xt, w_proj, w_out, wp, wo);
  k_qkv<<<dim3(SS / 64, O3 / 64, BB), 256, 0, stream>>>(xt, wp, b_proj, qh, ksw, vsw);
  k_attn<<<dim3(1024), 128, 0, stream>>>(qh, ksw, vsw, res);
  k_out<<<dim3(SS / 64, CC / 64, BB), 256, 0, stream>>>(res, wo, b_out, x, out);
}